// Round 6
// baseline (261.433 us; speedup 1.0000x reference)
//
#include <hip/hip_runtime.h>

#define M 4096
#define L 32
#define K 64
#define NBLK 256
#define BLOCK 1024
#define MK (M * K)
#define FLAG_BASE 0xAAAAAAAAu    // ws poison pattern; flag value = BASE + round

// Persistent kernel, flag-vector global barrier (R6).
// 256 blocks x 1024 threads; wave w of block b owns node m = 16*b + w;
// lane k owns in-edge k.
//
// Publish protocol (single-wave causality chain, verified R5):
//  - lane0 of each wave stashes val in LDS sres[16]; __syncthreads
//  - wave 0 lanes 0-15 publish the block's contiguous 16-float gbuf segment
//    with ONE agent-scope atomicExch (RMW executes at the coherence point;
//    asm use of the returned value forces the vmcnt wait)
//  - wave 0 lane 0 then stores flag[blk] = FLAG_BASE + round
//  - THEN prefetch issues (flag never gated by HBM prefetch drain — R5 bug)
// Wait: wave 0 polls all 256 flags as 4 coalesced 256B loads, ballot-AND.
__global__ __launch_bounds__(BLOCK, 4)
void net_kernel(const float* __restrict__ x,
                const float* __restrict__ w_in,
                const float* __restrict__ b_in,
                const float* __restrict__ w,
                const float* __restrict__ b,
                const int* __restrict__ igraf,
                float* __restrict__ out,
                unsigned* __restrict__ flags,
                float* __restrict__ gbuf)
{
    __shared__ float sv[M];       // full previous-layer value vector (16 KB)
    __shared__ float sres[16];    // this block's 16 freshly computed values

    const int tid  = threadIdx.x;
    const int blk  = blockIdx.x;
    const int wave = tid >> 6;
    const int lane = tid & 63;
    const int m    = blk * 16 + wave;
    const bool lastblk = (blk == NBLK - 1);   // owns node M-1

    // Layer-0 fragment prefetch.
    float wreg; int ireg; float breg;
    {
        const size_t b0 = (size_t)m * K + (size_t)lane;
        wreg = w[b0];
        ireg = igraf[b0];
        breg = b[m];
    }

    // v0 = relu(w_in * x + b_in), redundant per block, into LDS.
    {
        const float4 x4 = ((const float4*)x)[tid];
        const float4 wi = ((const float4*)w_in)[tid];
        const float4 bi = ((const float4*)b_in)[tid];
        float4 r;
        r.x = fmaxf(fmaf(wi.x, x4.x, bi.x), 0.0f);
        r.y = fmaxf(fmaf(wi.y, x4.y, bi.y), 0.0f);
        r.z = fmaxf(fmaf(wi.z, x4.z, bi.z), 0.0f);
        r.w = fmaxf(fmaf(wi.w, x4.w, bi.w), 0.0f);
        ((float4*)sv)[tid] = r;
    }
    __syncthreads();

    for (int l = 0; l < L; ++l) {
        // Gather + product (regs prefetched during previous spin window).
        float p = wreg * sv[ireg];

        // 64-lane butterfly reduction.
        #pragma unroll
        for (int off = 32; off > 0; off >>= 1)
            p += __shfl_xor(p, off, 64);

        const float val = 1.0f / (1.0f + __expf(-(p + breg)));

        if (l == L - 1) {
            if (lastblk && wave == 15 && lane == 0) out[0] = val;
            break;
        }

        if (lane == 0) sres[wave] = val;
        __syncthreads();

        // ---- publish + signal FIRST (nothing memory-heavy ahead of it) ----
        if (wave == 0) {
            if (lane < 16) {
                float old = __hip_atomic_exchange(
                    &gbuf[((l + 1) & 1) * M + blk * 16 + lane], sres[lane],
                    __ATOMIC_RELAXED, __HIP_MEMORY_SCOPE_AGENT);
                __asm__ volatile("" :: "v"(old));   // force RMW-ack wait
                if (lane == 0)
                    __hip_atomic_store(&flags[blk],
                                       FLAG_BASE + (unsigned)(l + 1),
                                       __ATOMIC_RELAXED,
                                       __HIP_MEMORY_SCOPE_AGENT);
            }
        }

        // Prefetch next layer AFTER the signal; drains during the spin.
        if ((l + 2 < L) || lastblk) {
            const size_t nb = (size_t)(l + 1) * MK + (size_t)m * K + (size_t)lane;
            wreg = w[nb];
            ireg = igraf[nb];
            breg = b[(l + 1) * M + m];
        }

        if ((l == L - 2) && !lastblk) return;  // only block 255 runs layer 31

        // Wait: 256 flags = 4 coalesced 256B loads, ballot-AND.
        if (wave == 0) {
            const unsigned tgt = FLAG_BASE + (unsigned)(l + 1);
            for (;;) {
                unsigned f0 = __hip_atomic_load(&flags[lane],
                        __ATOMIC_RELAXED, __HIP_MEMORY_SCOPE_AGENT);
                unsigned f1 = __hip_atomic_load(&flags[lane + 64],
                        __ATOMIC_RELAXED, __HIP_MEMORY_SCOPE_AGENT);
                unsigned f2 = __hip_atomic_load(&flags[lane + 128],
                        __ATOMIC_RELAXED, __HIP_MEMORY_SCOPE_AGENT);
                unsigned f3 = __hip_atomic_load(&flags[lane + 192],
                        __ATOMIC_RELAXED, __HIP_MEMORY_SCOPE_AGENT);
                const bool ok = (f0 >= tgt) & (f1 >= tgt) &
                                (f2 >= tgt) & (f3 >= tgt);
                if (__ballot(ok) == ~0ull) break;
                __builtin_amdgcn_s_sleep(4);
            }
        }
        __syncthreads();

        // Re-stage new v into LDS (sc1 loads: gbuf never cached in L1/L2).
        {
            const float* src = gbuf + ((l + 1) & 1) * M;
            #pragma unroll
            for (int j = 0; j < 4; ++j) {
                const int idx = tid + j * BLOCK;
                sv[idx] = __hip_atomic_load(&src[idx], __ATOMIC_RELAXED,
                                            __HIP_MEMORY_SCOPE_AGENT);
            }
        }
        __syncthreads();
    }
}

extern "C" void kernel_launch(void* const* d_in, const int* in_sizes, int n_in,
                              void* d_out, int out_size, void* d_ws, size_t ws_size,
                              hipStream_t stream) {
    const float* x     = (const float*)d_in[0];
    const float* w_in  = (const float*)d_in[1];
    const float* b_in  = (const float*)d_in[2];
    const float* wt    = (const float*)d_in[3];
    const float* b     = (const float*)d_in[4];
    const int*   igraf = (const int*)d_in[5];
    float*       out   = (float*)d_out;

    unsigned* flags = (unsigned*)d_ws;                 // 256 x u32, poison-proof
    float*    gbuf  = (float*)((char*)d_ws + 16384);   // 2 x M floats exchange

    // No memset: flags use absolute values biased by the 0xAA poison pattern.
    hipLaunchKernelGGL(net_kernel, dim3(NBLK), dim3(BLOCK), 0, stream,
                       x, w_in, b_in, wt, b, igraf, out, flags, gbuf);
    (void)in_sizes; (void)n_in; (void)out_size; (void)ws_size;
}

// Round 7
// 188.695 us; speedup vs baseline: 1.3855x; 1.3855x over previous
//
#include <hip/hip_runtime.h>

#define M 4096
#define L 32
#define K 64
#define NBLK 256
#define BLOCK 256
#define NPW 4                     // nodes per wave (4 waves/block -> 16 nodes)
#define NPB 16                    // nodes per block
#define MK (M * K)
#define FB 0xAAAAAAAAu            // ws poison; flag/release value = FB + round

// Persistent kernel (R7). 256 blocks x 256 threads (4 waves); wave w of
// block b owns nodes base..base+3, base = 16*b + 4*w; lane k owns in-edge k.
//
// Barrier: flag stores + single combiner.
//  - publish: wave0 lanes 0-15 atomicExch block's 16-float segment of the
//    ROUND-PRIVATE buffer buf[r] (RMW at coherence point; asm use of returned
//    value forces ack) -> lane0 stores flag[blk]=FB+r. Never gated by HBM
//    prefetch (prefetch issues after, and only on waves 1-3).
//  - combine: block 0 wave 0 polls 256 flags (4/lane, ONE block polling),
//    then stores a single release word = FB+r.
//  - wait: other blocks poll ONLY the release word (64 lanes, same address,
//    1 transaction/poll). No flat-poll mall flood (R5/R6 regression cause).
//  - restage: buf[r] is written once per launch and read only post-release;
//    kernel-dispatch acquire invalidates L1/L2, so NORMAL cached float4
//    loads are safe: one mall fill per XCD, L2 hits for the rest.
__global__ __launch_bounds__(BLOCK)
void net_kernel(const float* __restrict__ x,
                const float* __restrict__ w_in,
                const float* __restrict__ b_in,
                const float* __restrict__ w,
                const float* __restrict__ b,
                const int* __restrict__ igraf,
                float* __restrict__ out,
                unsigned* __restrict__ flags,
                unsigned* __restrict__ release,
                float* __restrict__ bufs)
{
    __shared__ float sv[M];       // previous-layer value vector (16 KB)
    __shared__ float sres[NPB];   // this block's 16 fresh values

    const int tid  = threadIdx.x;
    const int blk  = blockIdx.x;
    const int wave = tid >> 6;
    const int lane = tid & 63;
    const int base = blk * NPB + wave * NPW;
    const bool lastblk = (blk == NBLK - 1);   // owns node M-1
    const bool comb    = (blk == 0);          // combiner block

    // Layer-0 fragment prefetch (4 nodes/wave; bias on lanes 0-3).
    float wv[NPW]; int iv[NPW]; float breg = 0.0f;
    {
        const size_t b0 = (size_t)base * K + (size_t)lane;
        #pragma unroll
        for (int j = 0; j < NPW; ++j) {
            wv[j] = w[b0 + (size_t)j * K];
            iv[j] = igraf[b0 + (size_t)j * K];
        }
        if (lane < NPW) breg = b[base + lane];
    }

    // v0 = relu(w_in * x + b_in): 4 float4 per thread.
    #pragma unroll
    for (int j = 0; j < 4; ++j) {
        const int idx = tid + j * BLOCK;
        const float4 x4 = ((const float4*)x)[idx];
        const float4 wi = ((const float4*)w_in)[idx];
        const float4 bi = ((const float4*)b_in)[idx];
        float4 r;
        r.x = fmaxf(fmaf(wi.x, x4.x, bi.x), 0.0f);
        r.y = fmaxf(fmaf(wi.y, x4.y, bi.y), 0.0f);
        r.z = fmaxf(fmaf(wi.z, x4.z, bi.z), 0.0f);
        r.w = fmaxf(fmaf(wi.w, x4.w, bi.w), 0.0f);
        ((float4*)sv)[idx] = r;
    }
    __syncthreads();

    for (int l = 0; l < L; ++l) {
        // Gather + product, 4 independent nodes.
        float p[NPW];
        #pragma unroll
        for (int j = 0; j < NPW; ++j) p[j] = wv[j] * sv[iv[j]];

        // 4 independent 64-lane butterfly reductions.
        #pragma unroll
        for (int j = 0; j < NPW; ++j) {
            #pragma unroll
            for (int off = 32; off > 0; off >>= 1)
                p[j] += __shfl_xor(p[j], off, 64);
        }

        // Lane j (j<4) finalizes node base+j.
        float pj = p[0];
        pj = (lane == 1) ? p[1] : pj;
        pj = (lane == 2) ? p[2] : pj;
        pj = (lane == 3) ? p[3] : pj;
        const float val = 1.0f / (1.0f + __expf(-(pj + breg)));

        if (l == L - 1) {
            // Only block 255 reaches here. Unique writer: wave 3, lane 3
            // -> node 255*16 + 3*4 + 3 = 4095.  (R4 lesson: lane<4 qualify!)
            if (wave == 3 && lane == 3) out[0] = val;
            break;
        }

        if (lane < NPW) sres[wave * NPW + lane] = val;
        __syncthreads();

        const unsigned r = (unsigned)(l + 1);
        float* bufr = bufs + (size_t)r * M;

        // ---- publish + flag FIRST (wave 0; nothing memory-heavy ahead) ----
        if (wave == 0 && lane < NPB) {
            float old = __hip_atomic_exchange(
                &bufr[blk * NPB + lane], sres[lane],
                __ATOMIC_RELAXED, __HIP_MEMORY_SCOPE_AGENT);
            __asm__ volatile("" :: "v"(old));   // force RMW-ack before flag
            if (lane == 0)
                __hip_atomic_store(&flags[blk], FB + r,
                                   __ATOMIC_RELAXED, __HIP_MEMORY_SCOPE_AGENT);
        }

        // Prefetch next layer on waves 1-3 only (wave 0's poll must not be
        // vmcnt-gated behind HBM loads; R5/R6 flaw).
        const bool ok_next = (l + 2 < L) || lastblk;
        if (wave != 0 && ok_next) {
            const size_t nb = (size_t)(l + 1) * MK + (size_t)base * K + (size_t)lane;
            #pragma unroll
            for (int j = 0; j < NPW; ++j) {
                wv[j] = w[nb + (size_t)j * K];
                iv[j] = igraf[nb + (size_t)j * K];
            }
            if (lane < NPW) breg = b[(l + 1) * M + base + lane];
        }

        // ---- combine: block 0 wave 0 polls all flags, opens the gate ----
        if (comb && wave == 0) {
            const unsigned tgt = FB + r;
            for (;;) {
                unsigned f0 = __hip_atomic_load(&flags[lane],
                        __ATOMIC_RELAXED, __HIP_MEMORY_SCOPE_AGENT);
                unsigned f1 = __hip_atomic_load(&flags[lane + 64],
                        __ATOMIC_RELAXED, __HIP_MEMORY_SCOPE_AGENT);
                unsigned f2 = __hip_atomic_load(&flags[lane + 128],
                        __ATOMIC_RELAXED, __HIP_MEMORY_SCOPE_AGENT);
                unsigned f3 = __hip_atomic_load(&flags[lane + 192],
                        __ATOMIC_RELAXED, __HIP_MEMORY_SCOPE_AGENT);
                const bool ok = (f0 >= tgt) & (f1 >= tgt) &
                                (f2 >= tgt) & (f3 >= tgt);
                if (__ballot(ok) == ~0ull) break;
                __builtin_amdgcn_s_sleep(2);
            }
            __asm__ volatile("" ::: "memory");
            if (lane == 0)
                __hip_atomic_store(release, FB + r,
                                   __ATOMIC_RELAXED, __HIP_MEMORY_SCOPE_AGENT);
        }

        if ((l == L - 2) && !lastblk) return;  // all done except block 255

        // ---- wait: poll the single release word (1 transaction/poll) ----
        if (!comb && wave == 0) {
            const unsigned tgt = FB + r;
            while (__hip_atomic_load(release, __ATOMIC_RELAXED,
                                     __HIP_MEMORY_SCOPE_AGENT) < tgt)
                __builtin_amdgcn_s_sleep(2);
            __asm__ volatile("" ::: "memory");
        }
        __syncthreads();

        // Wave 0's prefetch, post-poll: drains alongside the restage loads.
        if (wave == 0 && ok_next) {
            const size_t nb = (size_t)(l + 1) * MK + (size_t)base * K + (size_t)lane;
            #pragma unroll
            for (int j = 0; j < NPW; ++j) {
                wv[j] = w[nb + (size_t)j * K];
                iv[j] = igraf[nb + (size_t)j * K];
            }
            if (lane < NPW) breg = b[(l + 1) * M + base + lane];
        }

        // Restage: normal cached vectorized loads from the round-private buf.
        {
            const float4* src = (const float4*)bufr;
            #pragma unroll
            for (int j = 0; j < 4; ++j) {
                const int idx = tid + j * BLOCK;
                ((float4*)sv)[idx] = src[idx];
            }
        }
        __syncthreads();
    }
}

extern "C" void kernel_launch(void* const* d_in, const int* in_sizes, int n_in,
                              void* d_out, int out_size, void* d_ws, size_t ws_size,
                              hipStream_t stream) {
    const float* x     = (const float*)d_in[0];
    const float* w_in  = (const float*)d_in[1];
    const float* b_in  = (const float*)d_in[2];
    const float* wt    = (const float*)d_in[3];
    const float* b     = (const float*)d_in[4];
    const int*   igraf = (const int*)d_in[5];
    float*       out   = (float*)d_out;

    unsigned* flags   = (unsigned*)d_ws;                  // 256 x u32
    unsigned* release = (unsigned*)((char*)d_ws + 4096);  // own cacheline
    float*    bufs    = (float*)((char*)d_ws + 16384);    // 32 x M floats

    // No memset: flags/release use absolute values biased by the 0xAA poison.
    hipLaunchKernelGGL(net_kernel, dim3(NBLK), dim3(BLOCK), 0, stream,
                       x, w_in, b_in, wt, b, igraf, out, flags, release, bufs);
    (void)in_sizes; (void)n_in; (void)out_size; (void)ws_size;
}

// Round 8
// 178.039 us; speedup vs baseline: 1.4684x; 1.0599x over previous
//
#include <hip/hip_runtime.h>

#define M 4096
#define L 32
#define K 64
#define NBLK 256
#define BLOCK 256
#define NPW 4                     // nodes per wave (4 waves -> 16 nodes/block)
#define NPB 16                    // nodes per block
#define MK (M * K)
#define FB 0xAAAAAAAAu            // ws poison; round tag = FB + round (r>=1)

// Persistent kernel (R8): dataflow-tagged exchange, NO barrier machinery.
// 256 blocks x 256 threads; wave w of block b owns nodes base..base+3,
// base = 16*b + 4*w; lane k owns in-edge k.
//
// Publish: node value as ONE tagged 8B sc1 store: (FB+r)<<32 | f32bits.
//   Aligned 8B stores are single-transaction: tag visible => value visible.
//   No RMW ack, no flags, no combiner, no release (R7's two-hop chain gone).
// Wait = restage: each thread sc1-loads its 16 strided u64s (coalesced
//   1KB/wave-instr), verifies hi-word == FB+r, re-loads only stale entries.
//   The poll IS the data read; straggler retries touch only stale lines.
// Versioning: double buffer (2 x 32KB). A block publishes r+1 only after
//   fully restaging r, which needs all blocks' r-publishes, which need their
//   (r-1)-restages -> blocks never 2 rounds apart -> 2 buffers suffice.
//   Tag equality rejects poison (FB+0) and stale rounds; no memset needed.
__global__ __launch_bounds__(BLOCK)
void net_kernel(const float* __restrict__ x,
                const float* __restrict__ w_in,
                const float* __restrict__ b_in,
                const float* __restrict__ w,
                const float* __restrict__ b,
                const int* __restrict__ igraf,
                float* __restrict__ out,
                unsigned long long* __restrict__ buf)   // 2 x M u64
{
    __shared__ float sv[M];   // previous-layer value vector (16 KB)

    const int tid  = threadIdx.x;
    const int blk  = blockIdx.x;
    const int wave = tid >> 6;
    const int lane = tid & 63;
    const int base = blk * NPB + wave * NPW;
    const bool lastblk = (blk == NBLK - 1);   // owns node M-1

    // Layer-0 fragment prefetch (4 nodes/wave; bias on lanes 0-3).
    float wv[NPW]; int iv[NPW]; float breg = 0.0f;
    {
        const size_t b0 = (size_t)base * K + (size_t)lane;
        #pragma unroll
        for (int j = 0; j < NPW; ++j) {
            wv[j] = w[b0 + (size_t)j * K];
            iv[j] = igraf[b0 + (size_t)j * K];
        }
        if (lane < NPW) breg = b[base + lane];
    }

    // v0 = relu(w_in * x + b_in): 4 float4 per thread.
    #pragma unroll
    for (int j = 0; j < 4; ++j) {
        const int idx = tid + j * BLOCK;
        const float4 x4 = ((const float4*)x)[idx];
        const float4 wi = ((const float4*)w_in)[idx];
        const float4 bi = ((const float4*)b_in)[idx];
        float4 r;
        r.x = fmaxf(fmaf(wi.x, x4.x, bi.x), 0.0f);
        r.y = fmaxf(fmaf(wi.y, x4.y, bi.y), 0.0f);
        r.z = fmaxf(fmaf(wi.z, x4.z, bi.z), 0.0f);
        r.w = fmaxf(fmaf(wi.w, x4.w, bi.w), 0.0f);
        ((float4*)sv)[idx] = r;
    }
    __syncthreads();

    for (int l = 0; l < L; ++l) {
        // Gather + product, 4 independent nodes.
        float p[NPW];
        #pragma unroll
        for (int j = 0; j < NPW; ++j) p[j] = wv[j] * sv[iv[j]];

        // 4 independent 64-lane butterfly reductions.
        #pragma unroll
        for (int j = 0; j < NPW; ++j) {
            #pragma unroll
            for (int off = 32; off > 0; off >>= 1)
                p[j] += __shfl_xor(p[j], off, 64);
        }

        // Lane j (j<4) finalizes node base+j.
        float pj = p[0];
        pj = (lane == 1) ? p[1] : pj;
        pj = (lane == 2) ? p[2] : pj;
        pj = (lane == 3) ? p[3] : pj;
        const float val = 1.0f / (1.0f + __expf(-(pj + breg)));

        if (l == L - 1) {
            // Only block 255 reaches l=31. Unique writer: wave 3 lane 3
            // -> node 255*16 + 3*4 + 3 = 4095.
            if (wave == 3 && lane == 3) out[0] = val;
            break;
        }

        const unsigned tag = FB + (unsigned)(l + 1);
        unsigned long long* bufr = buf + (size_t)((l + 1) & 1) * M;

        // ---- publish: tagged 8B store, self-validating, fire-and-forget ----
        if (lane < NPW) {
            const unsigned long long pk =
                ((unsigned long long)tag << 32) |
                (unsigned long long)__float_as_uint(val);
            __hip_atomic_store(&bufr[base + lane], pk,
                               __ATOMIC_RELAXED, __HIP_MEMORY_SCOPE_AGENT);
        }

        if ((l == L - 2) && !lastblk) return;  // all but block 255 done

        // Prefetch next layer (drains while we wait on tags).
        if ((l + 2 < L) || lastblk) {
            const size_t nb = (size_t)(l + 1) * MK + (size_t)base * K + (size_t)lane;
            #pragma unroll
            for (int j = 0; j < NPW; ++j) {
                wv[j] = w[nb + (size_t)j * K];
                iv[j] = igraf[nb + (size_t)j * K];
            }
            if (lane < NPW) breg = b[(l + 1) * M + base + lane];
        }

        // ---- restage pass 1: 16 strided u64/thread, coalesced sc1 loads ----
        unsigned long long vals[16];
        #pragma unroll
        for (int j = 0; j < 16; ++j)
            vals[j] = __hip_atomic_load(&bufr[tid + j * BLOCK],
                                        __ATOMIC_RELAXED,
                                        __HIP_MEMORY_SCOPE_AGENT);

        __syncthreads();   // all waves done gathering from OLD sv

        // ---- verify tags; re-load only stale entries ----
        for (;;) {
            bool ok = true;
            #pragma unroll
            for (int j = 0; j < 16; ++j) {
                if ((unsigned)(vals[j] >> 32) != tag) {
                    ok = false;
                    vals[j] = __hip_atomic_load(&bufr[tid + j * BLOCK],
                                                __ATOMIC_RELAXED,
                                                __HIP_MEMORY_SCOPE_AGENT);
                }
            }
            if (ok) break;
            __builtin_amdgcn_s_sleep(1);
        }

        // ---- write verified values into LDS ----
        #pragma unroll
        for (int j = 0; j < 16; ++j)
            sv[tid + j * BLOCK] = __uint_as_float((unsigned)vals[j]);
        __syncthreads();
    }
}

extern "C" void kernel_launch(void* const* d_in, const int* in_sizes, int n_in,
                              void* d_out, int out_size, void* d_ws, size_t ws_size,
                              hipStream_t stream) {
    const float* x     = (const float*)d_in[0];
    const float* w_in  = (const float*)d_in[1];
    const float* b_in  = (const float*)d_in[2];
    const float* wt    = (const float*)d_in[3];
    const float* b     = (const float*)d_in[4];
    const int*   igraf = (const int*)d_in[5];
    float*       out   = (float*)d_out;

    unsigned long long* buf = (unsigned long long*)d_ws;   // 2 x M x 8B = 64KB

    // No memset: poison hi-word = FB+0 never matches a round tag (FB+r, r>=1).
    hipLaunchKernelGGL(net_kernel, dim3(NBLK), dim3(BLOCK), 0, stream,
                       x, w_in, b_in, wt, b, igraf, out, buf);
    (void)in_sizes; (void)n_in; (void)out_size; (void)ws_size;
}